// Round 4
// baseline (63.902 us; speedup 1.0000x reference)
//
#include <hip/hip_runtime.h>
#include <hip/hip_bf16.h>
#include <math.h>

#define HH 192
#define WW 192
#define NPIX (HH * WW)
#define SCALE 0.25f   // head_dim(16)^-0.5

// per-head LDS region stride in dwords for the k/v halo (196 px * 8 dw + 4 pad)
#define REG 1572

static __device__ __forceinline__ float blo(unsigned int w) { return __uint_as_float(w << 16); }
static __device__ __forceinline__ float bhi(unsigned int w) { return __uint_as_float(w & 0xffff0000u); }

static __device__ __forceinline__ unsigned int pack_bf16(float a, float b)
{
    __hip_bfloat16 lo = __float2bfloat16(a);
    __hip_bfloat16 hi = __float2bfloat16(b);
    unsigned short ul, uh;
    __builtin_memcpy(&ul, &lo, 2);
    __builtin_memcpy(&uh, &hi, 2);
    return ((unsigned int)uh << 16) | ul;
}

// ---------------------------------------------------------------------------
// Kernel 1: fused Q/K/V projection, scalar-weight structure.
// x is [C=64][NPIX] f32. Outputs q,k,v all bf16 [NPIX][64] (packed dwords).
// Block = 512 threads = 8 waves over a 64-pixel tile:
//   lane  = pixel (coalesced x loads, L1-broadcast across waves)
//   wave& 3 = cout group (16 couts)  -> weights wave-uniform => s_load
//   wave>>2 = cin half (0..31 / 32..63) -> 2x wave parallelism
// Partial sums combined + transposed through LDS, coalesced bf16 stores.
// ---------------------------------------------------------------------------
__global__ __launch_bounds__(512) void qkv_kernel(
    const float* __restrict__ x,
    const float* __restrict__ wq, const float* __restrict__ wk,
    const float* __restrict__ wv,
    unsigned int* __restrict__ qg, unsigned int* __restrict__ kg,
    unsigned int* __restrict__ vg)
{
    __shared__ float lds[2 * 64 * 67];     // [cin-half][cout][px pad 67]
    const int t = threadIdx.x;
    const int lane = t & 63;                                  // pixel in tile
    const int cg = __builtin_amdgcn_readfirstlane((t >> 6) & 3);  // cout group
    const int ch = __builtin_amdgcn_readfirstlane(t >> 8);        // cin half
    const int pixel0 = blockIdx.x * 64;

    float aq[16], ak[16], av[16];
    #pragma unroll
    for (int cc = 0; cc < 16; ++cc) { aq[cc] = 0.f; ak[cc] = 0.f; av[cc] = 0.f; }

    const float* xp = x + pixel0 + lane;
    for (int ci = 0; ci < 32; ++ci) {
        const int cin = ch * 32 + ci;
        const float xv = xp[(size_t)cin * NPIX];
        const float* wqr = wq + cin * 64 + cg * 16;   // wave-uniform -> s_load
        const float* wkr = wk + cin * 64 + cg * 16;
        const float* wvr = wv + cin * 64 + cg * 16;
        #pragma unroll
        for (int cc = 0; cc < 16; ++cc) {
            aq[cc] = fmaf(xv, wqr[cc], aq[cc]);
            ak[cc] = fmaf(xv, wkr[cc], ak[cc]);
            av[cc] = fmaf(xv, wvr[cc], av[cc]);
        }
    }

    // per-matrix: write halves to LDS, combine, pack bf16, coalesced store
    const int px = t >> 3;             // readback pixel
    const int cd0 = (t & 7) * 4;       // 4 dwords (8 couts) per thread
    #pragma unroll
    for (int m = 0; m < 3; ++m) {
        const float* a = (m == 0) ? aq : (m == 1) ? ak : av;
        unsigned int* dst = (m == 0) ? qg : (m == 1) ? kg : vg;

        #pragma unroll
        for (int cc = 0; cc < 16; ++cc)
            lds[ch * (64 * 67) + (cg * 16 + cc) * 67 + lane] = a[cc];
        __syncthreads();

        unsigned int w[4];
        #pragma unroll
        for (int e = 0; e < 4; ++e) {
            const int c0 = (cd0 + e) * 2;
            const float f0 = lds[c0 * 67 + px] + lds[64 * 67 + c0 * 67 + px];
            const float f1 = lds[(c0 + 1) * 67 + px] + lds[64 * 67 + (c0 + 1) * 67 + px];
            w[e] = pack_bf16(f0, f1);
        }
        *reinterpret_cast<uint4*>(dst + (size_t)(pixel0 + px) * 32 + cd0) =
            make_uint4(w[0], w[1], w[2], w[3]);
        __syncthreads();
    }
}

// ---------------------------------------------------------------------------
// Kernel 2: tiled neighborhood attention + fused output projection.
// Block = 512 threads: 8x8 pixel tile x 4 heads x 2 neighbor-halves.
// 576 blocks, XCD-swizzled (3 contiguous tile-rows per XCD ~= its 4MB L2).
// k,v halo (14x14, bf16, per-head LDS regions) + block-uniform sims staged.
// Even/odd neighbor halves combined via shfl_xor(1); projection through LDS.
// ---------------------------------------------------------------------------
__global__ __launch_bounds__(512) void attn_proj_kernel(
    const unsigned int* __restrict__ qg,
    const unsigned int* __restrict__ kg,
    const unsigned int* __restrict__ vg,
    const float* __restrict__ sims,
    const float* __restrict__ wp,
    float* __restrict__ out)
{
    __shared__ unsigned int smem[8 * REG + 256];   // k[4][REG], v[4][REG], sims[196]

    const int bid = blockIdx.x;
    const int tl = (bid & 7) * 72 + (bid >> 3);    // XCD swizzle (576 = 8*72)
    const int ty = tl / 24, tx = tl - ty * 24;
    const int Y0 = ty * 8, X0 = tx * 8;
    int hy0 = Y0 - 3; hy0 = hy0 < 0 ? 0 : (hy0 > HH - 14 ? HH - 14 : hy0);
    int hx0 = X0 - 3; hx0 = hx0 < 0 ? 0 : (hx0 > WW - 14 ? WW - 14 : hx0);
    const int t = threadIdx.x;

    // ---- stage k,v halo: 196 rows x 128B = 1568 dwordx4 units per tensor
    #pragma unroll
    for (int i = 0; i < 4; ++i) {
        const int idx = i * 512 + t;
        if (idx < 1568) {
            const int hidx = idx >> 3;
            const int u = idx & 7;
            const int r = hidx / 14;
            const int c = hidx - r * 14;
            const int np = (hy0 + r) * WW + hx0 + c;
            const uint4 kk = *reinterpret_cast<const uint4*>(kg + (size_t)np * 32 + u * 4);
            const uint4 vv = *reinterpret_cast<const uint4*>(vg + (size_t)np * 32 + u * 4);
            const int h = u >> 1, hf = u & 1;
            unsigned int* dk = smem + h * REG + hidx * 8 + hf * 4;
            *reinterpret_cast<uint4*>(dk) = kk;
            *reinterpret_cast<uint4*>(dk + 4 * REG) = vv;
        }
    }
    if (t < 196) {
        const int r = t / 14;
        const int c = t - r * 14;
        const int np = (hy0 + r) * WW + hx0 + c;
        const int sbase = (Y0 >> 4) * 12 + (X0 >> 4);   // block-uniform
        reinterpret_cast<float*>(smem)[8 * REG + t] = sims[np * 144 + sbase];
    }
    __syncthreads();

    // ---- attention: thread = (pixel, head, neighbor-half)
    const int p = t >> 3, h = (t >> 1) & 3, half = t & 1;
    const int py = p >> 3, pxq = p & 7;
    const int y = Y0 + py, xq = X0 + pxq;
    int sy = y - 3;  sy = sy < 0 ? 0 : (sy > HH - 7 ? HH - 7 : sy);
    int sx = xq - 3; sx = sx < 0 ? 0 : (sx > WW - 7 ? WW - 7 : sx);
    const int wbase = (sy - hy0) * 14 + (sx - hx0);

    // load + unpack q (bf16) once
    float qv[16];
    {
        const unsigned int* qp = qg + (size_t)(y * WW + xq) * 32 + h * 8;
        const uint4 a = *reinterpret_cast<const uint4*>(qp);
        const uint4 b = *reinterpret_cast<const uint4*>(qp + 4);
        const unsigned int qs[8] = { a.x, a.y, a.z, a.w, b.x, b.y, b.z, b.w };
        #pragma unroll
        for (int e = 0; e < 8; ++e) { qv[2 * e] = blo(qs[e]); qv[2 * e + 1] = bhi(qs[e]); }
    }

    const unsigned int* kreg = smem + h * REG;
    const unsigned int* vreg = kreg + 4 * REG;
    const float* sm = reinterpret_cast<const float*>(smem + 8 * REG);

    float S = 0.f;
    float acc[16];
    #pragma unroll
    for (int d = 0; d < 16; ++d) acc[d] = 0.f;

    #pragma unroll
    for (int i = 0; i < 25; ++i) {
        const int nn = 2 * i + half;
        if (nn < 49) {
            const int ky = (nn * 37) >> 8;        // nn/7 for nn<56
            const int kx = nn - 7 * ky;
            const int hidx = wbase + ky * 14 + kx;

            const uint4 ka = *reinterpret_cast<const uint4*>(kreg + hidx * 8);
            const uint4 k2 = *reinterpret_cast<const uint4*>(kreg + hidx * 8 + 4);
            float d0 = qv[0] * blo(ka.x), d1 = qv[1] * bhi(ka.x);
            float d2 = qv[2] * blo(ka.y), d3 = qv[3] * bhi(ka.y);
            d0 = fmaf(qv[4],  blo(ka.z), d0); d1 = fmaf(qv[5],  bhi(ka.z), d1);
            d2 = fmaf(qv[6],  blo(ka.w), d2); d3 = fmaf(qv[7],  bhi(ka.w), d3);
            d0 = fmaf(qv[8],  blo(k2.x), d0); d1 = fmaf(qv[9],  bhi(k2.x), d1);
            d2 = fmaf(qv[10], blo(k2.y), d2); d3 = fmaf(qv[11], bhi(k2.y), d3);
            d0 = fmaf(qv[12], blo(k2.z), d0); d1 = fmaf(qv[13], bhi(k2.z), d1);
            d2 = fmaf(qv[14], blo(k2.w), d2); d3 = fmaf(qv[15], bhi(k2.w), d3);
            const float dot = (d0 + d1) + (d2 + d3);

            const float m = sm[hidx];
            const float pf = __expf(SCALE * dot * m);
            S += pf;
            const float pm = pf * m;

            const uint4 va = *reinterpret_cast<const uint4*>(vreg + hidx * 8);
            const uint4 v2 = *reinterpret_cast<const uint4*>(vreg + hidx * 8 + 4);
            acc[0]  = fmaf(pm, blo(va.x), acc[0]);
            acc[1]  = fmaf(pm, bhi(va.x), acc[1]);
            acc[2]  = fmaf(pm, blo(va.y), acc[2]);
            acc[3]  = fmaf(pm, bhi(va.y), acc[3]);
            acc[4]  = fmaf(pm, blo(va.z), acc[4]);
            acc[5]  = fmaf(pm, bhi(va.z), acc[5]);
            acc[6]  = fmaf(pm, blo(va.w), acc[6]);
            acc[7]  = fmaf(pm, bhi(va.w), acc[7]);
            acc[8]  = fmaf(pm, blo(v2.x), acc[8]);
            acc[9]  = fmaf(pm, bhi(v2.x), acc[9]);
            acc[10] = fmaf(pm, blo(v2.y), acc[10]);
            acc[11] = fmaf(pm, bhi(v2.y), acc[11]);
            acc[12] = fmaf(pm, blo(v2.z), acc[12]);
            acc[13] = fmaf(pm, bhi(v2.z), acc[13]);
            acc[14] = fmaf(pm, blo(v2.w), acc[14]);
            acc[15] = fmaf(pm, bhi(v2.w), acc[15]);
        }
    }

    // combine even/odd neighbor halves (adjacent lanes)
    const float S2 = S + __shfl_xor(S, 1, 64);
    float comb[16];
    #pragma unroll
    for (int j = 0; j < 16; ++j)
        comb[j] = acc[j] + __shfl_xor(acc[j], 1, 64);
    const float inv = 1.f / S2;

    // ---- fused projection through LDS (attn-out transposed, pad 67)
    __syncthreads();                   // all k/v/sims LDS reads done
    float* os = reinterpret_cast<float*>(smem);   // [64 cout][67]
    #pragma unroll
    for (int jj = 0; jj < 8; ++jj)
        os[(h * 16 + half * 8 + jj) * 67 + p] = comb[half * 8 + jj] * inv;
    __syncthreads();

    const int pix2 = t & 63;
    const int cgp = __builtin_amdgcn_readfirstlane(t >> 6);   // 0..7, wave-uniform
    float o2[8];
    #pragma unroll
    for (int cc = 0; cc < 8; ++cc) o2[cc] = 0.f;

    for (int cin = 0; cin < 64; ++cin) {
        const float xv = os[cin * 67 + pix2];
        #pragma unroll
        for (int cc = 0; cc < 8; ++cc)
            o2[cc] = fmaf(xv, wp[cin * 64 + cgp * 8 + cc], o2[cc]);
    }

    const int gy = Y0 + (pix2 >> 3), gx = X0 + (pix2 & 7);
    #pragma unroll
    for (int cc = 0; cc < 8; ++cc)
        out[(size_t)(cgp * 8 + cc) * NPIX + gy * WW + gx] = o2[cc];
}

// ---------------------------------------------------------------------------
extern "C" void kernel_launch(void* const* d_in, const int* in_sizes, int n_in,
                              void* d_out, int out_size, void* d_ws, size_t ws_size,
                              hipStream_t stream)
{
    const float* x    = (const float*)d_in[0];
    const float* sims = (const float*)d_in[1];
    const float* wq   = (const float*)d_in[2];
    const float* wk   = (const float*)d_in[3];
    const float* wv   = (const float*)d_in[4];
    const float* wp   = (const float*)d_in[5];
    float* out = (float*)d_out;

    unsigned int* qg = (unsigned int*)d_ws;            // bf16x2 [NPIX][32]
    unsigned int* kg = qg + (size_t)NPIX * 32;
    unsigned int* vg = kg + (size_t)NPIX * 32;

    qkv_kernel<<<NPIX / 64, 512, 0, stream>>>(x, wq, wk, wv, qg, kg, vg);
    attn_proj_kernel<<<576, 512, 0, stream>>>(qg, kg, vg, sims, wp, out);
}